// Round 2
// baseline (7538.815 us; speedup 1.0000x reference)
//
#include <hip/hip_runtime.h>
#include <hip/hip_bf16.h>
#include <stdint.h>
#include <stddef.h>

// LSTM: T=2048, B=64, D=256, H=256, L=2. Layers independent (both read original x).
// Persistent recurrent kernel: 32 WGs per layer, each owns 8 h-cols (32 gate cols),
// W slice register-resident as MFMA B-frags, c in registers, h broadcast via
// MALL-coherent (sc0 sc1) global buffer + per-WG monotonic step flags.

typedef __bf16 bf16x8 __attribute__((ext_vector_type(8)));
typedef float f32x4 __attribute__((ext_vector_type(4)));

#define T_STEPS 2048
#define BATCH   64
#define DIM     256
#define HID     256
#define NLAYER  2

// ---------------- coherent memory helpers (cross-XCD via MALL) ----------------
__device__ __forceinline__ bf16x8 ld_cohere_b128(const __bf16* p) {
  bf16x8 r;
  asm volatile("global_load_dwordx4 %0, %1, off sc0 sc1" : "=v"(r) : "v"(p) : "memory");
  return r;
}
__device__ __forceinline__ unsigned ld_cohere_u32(const unsigned* p) {
  unsigned r;
  asm volatile("global_load_dword %0, %1, off sc0 sc1\n\ts_waitcnt vmcnt(0)"
               : "=v"(r) : "v"(p) : "memory");
  return r;
}
__device__ __forceinline__ void st_cohere_u16(__bf16* p, unsigned v) {
  asm volatile("global_store_short %0, %1, off sc0 sc1" :: "v"(p), "v"(v) : "memory");
}
__device__ __forceinline__ void st_cohere_u32(unsigned* p, unsigned v) {
  asm volatile("global_store_dword %0, %1, off sc0 sc1" :: "v"(p), "v"(v) : "memory");
}
__device__ __forceinline__ void waitcnt_vm0() {
  asm volatile("s_waitcnt vmcnt(0)" ::: "memory");
}

__device__ __forceinline__ float fast_sigmoid(float x) {
  return __builtin_amdgcn_rcpf(1.f + __expf(-x));
}
__device__ __forceinline__ float fast_tanh(float x) {
  float xc = fminf(15.f, fmaxf(-15.f, x));
  float e = __expf(-2.f * xc);
  return (1.f - e) * __builtin_amdgcn_rcpf(1.f + e);
}

// ---------------- pass 0a: cast x to bf16 ----------------
__global__ void cast_x_kernel(const float* __restrict__ x, __bf16* __restrict__ xb) {
  size_t i = (size_t)blockIdx.x * blockDim.x + threadIdx.x;  // 0 .. 4194303
  const float4* xv = (const float4*)x;
  float4 a = xv[i * 2];
  float4 b = xv[i * 2 + 1];
  bf16x8 o;
  o[0] = (__bf16)a.x; o[1] = (__bf16)a.y; o[2] = (__bf16)a.z; o[3] = (__bf16)a.w;
  o[4] = (__bf16)b.x; o[5] = (__bf16)b.y; o[6] = (__bf16)b.z; o[7] = (__bf16)b.w;
  *(bf16x8*)(xb + i * 8) = o;
}

// ---------------- pass 0b: init flags + h0 (bf16, parity 0) ----------------
__global__ void init_kernel(const float* __restrict__ h0,
                            __bf16* __restrict__ hbuf, unsigned* __restrict__ flags) {
  int tid = threadIdx.x;
  for (int i = tid; i < 1024; i += 256) flags[i] = 0u;          // 2 layers * 32 WGs * 16 pad
  for (int i = tid; i < NLAYER * BATCH * HID; i += 256)
    hbuf[i] = (__bf16)h0[i];                                    // parity-0 buffers
}

// ---------------- persistent recurrent kernel ----------------
// grid = 64 blocks x 256 threads. block = (layer = bid>>5, w = bid&31).
// Wave m handles batch rows [16m,16m+16). N-tile0 cols: f(j),i(j); N-tile1: g(j),o(j),
// j in [w*8, w*8+8). MFMA 16x16x32 layouts:
//   A[row=lane&15][k=8*(lane>>4)+e]   B[k=8*(lane>>4)+e][col=lane&15]
//   D[row=4*(lane>>4)+r][col=lane&15]
__global__ __launch_bounds__(256, 1) void lstm_rec_kernel(
    const float* __restrict__ xf, const __bf16* __restrict__ xb, int use_xb,
    const float* __restrict__ W, const float* __restrict__ bias,
    const float* __restrict__ c0,
    __bf16* __restrict__ hbuf, unsigned* __restrict__ flags,
    float* __restrict__ out)
{
  const int bid   = blockIdx.x;
  const int l     = bid >> 5;
  const int w     = bid & 31;
  const int tid   = threadIdx.x;
  const int lane  = tid & 63;
  const int wavem = tid >> 6;
  const int lo16  = lane & 15;
  const int kblk  = lane >> 4;

  // gate-column mapping for this lane (W cols: f | i | g | o)
  const int col0 = (lo16 < 8) ? (w * 8 + lo16) : (256 + w * 8 + (lo16 - 8));      // f / i
  const int col1 = (lo16 < 8) ? (512 + w * 8 + lo16) : (768 + w * 8 + (lo16 - 8)); // g / o

  // one-time: gather W slice into register-resident B fragments (bf16)
  const float* Wl = W + (size_t)l * 512 * 1024;
  bf16x8 bfr[2][16];
#pragma unroll
  for (int kk = 0; kk < 16; ++kk) {
    const int k0 = kk * 32 + kblk * 8;
    bf16x8 t0, t1;
#pragma unroll
    for (int e = 0; e < 8; ++e) {
      t0[e] = (__bf16)Wl[(size_t)(k0 + e) * 1024 + col0];
      t1[e] = (__bf16)Wl[(size_t)(k0 + e) * 1024 + col1];
    }
    bfr[0][kk] = t0;
    bfr[1][kk] = t1;
  }
  const float bias0 = bias[l * 1024 + col0];
  const float bias1 = bias[l * 1024 + col1];

  const int jcol = w * 8 + (lo16 & 7);       // h column owned (valid when lo16<8)
  const int arow = wavem * 16 + lo16;        // A-operand batch row

  float creg[4], hval[4];
#pragma unroll
  for (int r = 0; r < 4; ++r) {
    const int brow = wavem * 16 + kblk * 4 + r;
    creg[r] = c0[l * (BATCH * HID) + brow * HID + jcol];
    hval[r] = 0.f;
  }

  __bf16* hb0 = hbuf + (size_t)l * (BATCH * HID);                  // parity 0
  __bf16* hb1 = hbuf + (size_t)(NLAYER + l) * (BATCH * HID);       // parity 1
  unsigned* myflags = flags + l * 512;                             // 32 slots x 16 u32

  int dead = 0;

  for (int s = 1; s <= T_STEPS; ++s) {
    const int t = s - 1;
    bf16x8 af[16];

    // x-part A fragments (independent of recurrence -> issue before polling)
    if (use_xb) {
      const __bf16* xrow = xb + ((size_t)t * BATCH + arow) * DIM + kblk * 8;
#pragma unroll
      for (int kk = 0; kk < 8; ++kk)
        af[kk] = *(const bf16x8*)(xrow + kk * 32);
    } else {
      const float* xrow = xf + ((size_t)t * BATCH + arow) * DIM + kblk * 8;
#pragma unroll
      for (int kk = 0; kk < 8; ++kk) {
        float4 a = *(const float4*)(xrow + kk * 32);
        float4 b4 = *(const float4*)(xrow + kk * 32 + 4);
        bf16x8 v;
        v[0] = (__bf16)a.x;  v[1] = (__bf16)a.y;  v[2] = (__bf16)a.z;  v[3] = (__bf16)a.w;
        v[4] = (__bf16)b4.x; v[5] = (__bf16)b4.y; v[6] = (__bf16)b4.z; v[7] = (__bf16)b4.w;
        af[kk] = v;
      }
    }

    // wave 0 polls until all WGs of this layer finished step s-1; bounded spin.
    if (s > 1) {
      if (wavem == 0 && !dead) {
        const unsigned target = (unsigned)(s - 1);
        int iters = 0;
        for (;;) {
          unsigned v = ld_cohere_u32(&myflags[(lane & 31) * 16]);
          if (__all((int)(v >= target))) break;
          if (++iters > (1 << 21)) { dead = 1; break; }   // bailout: fail fast, no hang
          __builtin_amdgcn_s_sleep(1);
        }
      }
      __syncthreads();
    }

    // h-part A fragments: coherent loads from the parity buffer of h[s-1]
    const __bf16* hread = ((s - 1) & 1) ? hb1 : hb0;
    const __bf16* hrow = hread + arow * HID + kblk * 8;
#pragma unroll
    for (int kk = 0; kk < 8; ++kk)
      af[8 + kk] = ld_cohere_b128(hrow + kk * 32);
    waitcnt_vm0();
    __builtin_amdgcn_sched_barrier(0);   // keep MFMAs after the waitcnt (rule 18)

    f32x4 acc0 = {0.f, 0.f, 0.f, 0.f};
    f32x4 acc1 = {0.f, 0.f, 0.f, 0.f};
#pragma unroll
    for (int kk = 0; kk < 16; ++kk) {
      acc0 = __builtin_amdgcn_mfma_f32_16x16x32_bf16(af[kk], bfr[0][kk], acc0, 0, 0, 0);
      acc1 = __builtin_amdgcn_mfma_f32_16x16x32_bf16(af[kk], bfr[1][kk], acc1, 0, 0, 0);
    }

    // epilogue: combine f,i,g,o via xor-8 shuffles; update c,h (lanes lo16<8 own data)
    __bf16* hwrite = (s & 1) ? hb1 : hb0;
#pragma unroll
    for (int r = 0; r < 4; ++r) {
      float s0 = acc0[r] + bias0;          // f_pre (lo16<8) / i_pre (lo16>=8)
      float s1 = acc1[r] + bias1;          // g_pre / o_pre
      float ipre = __shfl_xor(s0, 8);
      float opre = __shfl_xor(s1, 8);
      float fg = fast_sigmoid(s0);
      float ig = fast_sigmoid(ipre);
      float gg = fast_tanh(s1);
      float og = fast_sigmoid(opre);
      float cn = fg * creg[r] + ig * gg;
      creg[r] = cn;
      hval[r] = og * fast_tanh(cn);
    }
    if (lo16 < 8) {
#pragma unroll
      for (int r = 0; r < 4; ++r) {       // h first: starts the visibility path earliest
        const int brow = wavem * 16 + kblk * 4 + r;
        __bf16 hv = (__bf16)hval[r];
        unsigned u = (unsigned)__builtin_bit_cast(unsigned short, hv);
        st_cohere_u16(hwrite + brow * HID + jcol, u);
      }
      if (l == 1) {
#pragma unroll
        for (int r = 0; r < 4; ++r) {
          const int brow = wavem * 16 + kblk * 4 + r;
          __builtin_nontemporal_store(hval[r], &out[(size_t)t * (BATCH * HID) + brow * HID + jcol]);
        }
      }
    }

    waitcnt_vm0();        // h slice visible at the coherence point (sc0 sc1 stores)
    __syncthreads();      // all 4 waves of this WG done
    if (tid == 0)
      st_cohere_u32(&myflags[w * 16], (unsigned)s);
  }

  // final hT, cT
  if (lo16 < 8) {
    float* hs = out + (size_t)T_STEPS * BATCH * HID;   // [L,B,H]
    float* cs = hs + NLAYER * BATCH * HID;
#pragma unroll
    for (int r = 0; r < 4; ++r) {
      const int brow = wavem * 16 + kblk * 4 + r;
      hs[l * (BATCH * HID) + brow * HID + jcol] = hval[r];
      cs[l * (BATCH * HID) + brow * HID + jcol] = creg[r];
    }
  }
}

extern "C" void kernel_launch(void* const* d_in, const int* in_sizes, int n_in,
                              void* d_out, int out_size, void* d_ws, size_t ws_size,
                              hipStream_t stream) {
  const float* x  = (const float*)d_in[0];   // [T,B,D]
  const float* h0 = (const float*)d_in[1];   // [L,B,H]
  const float* c0 = (const float*)d_in[2];   // [L,B,H]
  const float* W  = (const float*)d_in[3];   // [L,512,1024]
  const float* b  = (const float*)d_in[4];   // [L,1024]
  float* out = (float*)d_out;
  char* ws = (char*)d_ws;

  unsigned* flags = (unsigned*)ws;                       // 4096 B
  __bf16* hbuf    = (__bf16*)(ws + 4096);                // 2 parity * 2 layers * 64*256 * 2B = 128 KiB
  __bf16* xb      = (__bf16*)(ws + 4096 + 131072);       // 64 MiB bf16 x

  const size_t need = 4096 + 131072 + (size_t)T_STEPS * BATCH * DIM * 2;
  const int use_xb = (ws_size >= need) ? 1 : 0;

  if (use_xb)
    cast_x_kernel<<<dim3(16384), dim3(256), 0, stream>>>(x, xb);
  init_kernel<<<dim3(1), dim3(256), 0, stream>>>(h0, hbuf, flags);
  lstm_rec_kernel<<<dim3(64), dim3(256), 0, stream>>>(x, xb, use_xb, W, b, c0,
                                                      hbuf, flags, out);
}